// Round 13
// baseline (348.029 us; speedup 1.0000x reference)
//
#include <hip/hip_runtime.h>
#include <stdint.h>

// Match numpy semantics: no FMA contraction anywhere in decision-critical math.
#pragma clang fp contract(off)

#define N_ANCHORS 172032  // compile-time problem constant
#define MAX_OUT 200
#define KTOP 2048         // top-K prefix capacity (= 32 chunk-words of 64 ranks)
#define NCHUNK (KTOP / 64)
#define BLK 1024
#define NW (BLK / 64)
#define VT 2.35f          // fixed prefix threshold: scores ~ N(0,1) =>
                          // csel = 172032*P(N>2.35) ~ 1615 +/- 40 (5sig < 2048).
                          // Exact fallback guards overflow AND exhaustion.

typedef unsigned long long ull;

// f64 decode: f32 inputs upcast to f64, reference op order. Returns (y1,x1,y2,x2).
__device__ __forceinline__ void decode_box_d(const float4* __restrict__ reg,
                                             const float4* __restrict__ anc, int i,
                                             double b[4]) {
#pragma clang fp contract(off)
    float4 r = reg[i];
    float4 a = anc[i];
    double dx = (double)r.x * 0.1;
    double dy = (double)r.y * 0.1;
    double dw = (double)r.z * 0.2;
    double dh = (double)r.w * 0.2;
    double xa = (double)a.x, ya = (double)a.y, wa = (double)a.z, ha = (double)a.w;
    double xc = dx * wa; xc = xc + xa;     // dx*w_a + x_a
    double yc = dy * ha; yc = yc + ya;     // dy*h_a + y_a
    double w = exp(dw) * wa;
    double h = exp(dh) * ha;
    double h2 = h * 0.5, w2 = w * 0.5;
    b[0] = yc - h2; b[1] = xc - w2; b[2] = yc + h2; b[3] = xc + w2;
}

// Gather + f64 decode one output row (boxes + landmarks), write f32.
__device__ __forceinline__ void write_row(const float4* __restrict__ reg,
                                          const float4* __restrict__ anc,
                                          const float* __restrict__ lnd,
                                          int q, int idx, float* __restrict__ out) {
#pragma clang fp contract(off)
    float b[4] = {0.f, 0.f, 0.f, 0.f};
    float l10[10] = {0.f, 0.f, 0.f, 0.f, 0.f, 0.f, 0.f, 0.f, 0.f, 0.f};
    if (idx >= 0) {
        double bb[4];
        decode_box_d(reg, anc, idx, bb);
        b[0] = (float)bb[0]; b[1] = (float)bb[1]; b[2] = (float)bb[2]; b[3] = (float)bb[3];
        float4 a = anc[idx];
        double xa = (double)a.x, ya = (double)a.y, wa = (double)a.z, ha = (double)a.w;
        for (int j = 0; j < 5; ++j) {
            double lx = (double)lnd[idx * 10 + 2 * j]     * 0.1;
            double ly = (double)lnd[idx * 10 + 2 * j + 1] * 0.1;
            lx = lx * wa; lx = lx + xa;
            ly = ly * ha; ly = ly + ya;
            l10[2 * j] = (float)lx; l10[2 * j + 1] = (float)ly;
        }
    }
    for (int c = 0; c < 4; ++c)  out[q * 4 + c] = b[c];
    for (int c = 0; c < 10; ++c) out[MAX_OUT * 4 + q * 10 + c] = l10[c];
}

__device__ __forceinline__ ull wmax(ull k) {
    for (int d = 32; d > 0; d >>= 1) {
        ull o = __shfl_down(k, d, 64);
        if (o > k) k = o;
    }
    return k;
}

// ---------- kernel 1: compact top candidates (fixed threshold) ----------
__global__ void k_compact_top(const float2* __restrict__ cls, int n,
                              int* __restrict__ ctr, ull* __restrict__ keys) {
    int i = blockIdx.x * blockDim.x + threadIdx.x;
    if (i >= n) return;
    float sc = cls[i].y;                       // score = cls[:,1]
    if (sc > VT) {
        int pos = atomicAdd(&ctr[0], 1);
        if (pos < KTOP)
            keys[pos] = ((ull)__float_as_uint(sc) << 32)
                      | (ull)(0xFFFFFFFFu - (unsigned int)i);
    }
}

// ---------- kernel 2: fused rank-sort + chunked greedy NMS + output ----------
__global__ void __launch_bounds__(BLK) k_fused(const float4* __restrict__ reg,
                                               const float4* __restrict__ anc,
                                               const float* __restrict__ lnd,
                                               const int* __restrict__ ctr,
                                               const ull* __restrict__ gkeys,
                                               int* __restrict__ flag,
                                               float* __restrict__ out) {
    __shared__ ull ubuf[KTOP];           // 16 KB: phase A = keys; phase B = 64x32 bit-block
    __shared__ float4 sbox[KTOP];        // 32 KB: boxes in rank order
    __shared__ int ssidx[KTOP];          // 8 KB: original index in rank order
    __shared__ int s_kept[MAX_OUT];
    __shared__ int s_ln;

    int tid = threadIdx.x;
    int csel = ctr[0];
    if (csel > KTOP) { if (tid == 0) *flag = 1; return; }   // overflow -> fallback

    for (int j = tid; j < KTOP; j += BLK) ubuf[j] = (j < csel) ? gkeys[j] : 0ull;
    for (int r = csel + tid; r < KTOP; r += BLK) {          // padding slots only
        ssidx[r] = -1;
        sbox[r] = make_float4(0.f, 0.f, 0.f, 0.f);
    }
    if (tid == 0) s_ln = 0;
    __syncthreads();

    // rank-by-counting (keys unique; zeros rank >= csel, handled by padding init)
    ull my0 = ubuf[tid], my1 = ubuf[tid + BLK];
    int r0 = 0, r1 = 0;
    for (int j = 0; j < KTOP; ++j) {
        ull k = ubuf[j];                 // broadcast read
        r0 += (k > my0) ? 1 : 0;
        r1 += (k > my1) ? 1 : 0;
    }
    if (my0 != 0ull) {
        int idx = (int)(0xFFFFFFFFu - (unsigned int)my0);
        double b[4]; decode_box_d(reg, anc, idx, b);
        sbox[r0] = make_float4((float)b[0], (float)b[1], (float)b[2], (float)b[3]);
        ssidx[r0] = idx;
    }
    if (my1 != 0ull) {
        int idx = (int)(0xFFFFFFFFu - (unsigned int)my1);
        double b[4]; decode_box_d(reg, anc, idx, b);
        sbox[r1] = make_float4((float)b[0], (float)b[1], (float)b[2], (float)b[3]);
        ssidx[r1] = idx;
    }
    __syncthreads();                     // last ubuf(keys) read above; mat writes below

    // per-lane removed word: lane w (w<32) holds ranks [64w, 64w+64); ranks >= csel pre-removed
    ull rm = 0;
    if (tid < 32) {
        int rbase = tid << 6;
        if (rbase >= csel) rm = ~0ull;
        else if (rbase + 64 > csel) rm = ~((1ull << (csel - rbase)) - 1ull);
    }

    for (int c = 0; c < NCHUNK; ++c) {
        if (s_ln >= MAX_OUT) break;      // uniform: read after a barrier
        int base = c << 6;
        if (base >= csel) break;         // candidates exhausted
        // speculative 64-row suppression bit-block for ranks [base, base+64),
        // words wl in [c, 32) only (cols j <= base never needed)
        int nw = NCHUNK - c;
        for (int q = tid; q < 64 * nw; q += BLK) {
            int rl = q & 63;             // row within chunk (= lane id -> bcast col reads)
            int wl = c + (q >> 6);       // 64-col word (uniform per wave)
            int ig = base + rl;          // global rank of row
            float4 bi = sbox[ig];
            double q0 = (double)bi.x, q1 = (double)bi.y, q2 = (double)bi.z, q3 = (double)bi.w;
            double ai = (q2 - q0) * (q3 - q1);
            ull bits = 0;
            int j0 = wl << 6;
            for (int b = 0; b < 64; ++b) {
                int j = j0 + b;
                if (j > ig) {
                    float4 bj = sbox[j];     // same addr across wave -> broadcast
                    double y1 = (double)bj.x, x1 = (double)bj.y;
                    double y2 = (double)bj.z, x2 = (double)bj.w;
                    double ih = fmin(y2, q2) - fmax(y1, q0); ih = fmax(ih, 0.0);
                    double iw = fmin(x2, q3) - fmax(x1, q1); iw = fmax(iw, 0.0);
                    double inter = ih * iw;
                    double aj = (y2 - y1) * (x2 - x1);
                    double den = aj + ai; den = den - inter; den = den + 1e-12;
                    if (inter / den > 0.4) bits |= (1ull << b);
                }
            }
            ubuf[rl * 32 + wl] = bits;
        }
        __syncthreads();
        // wave-0 barrier-free scan of chunk word c (removed-set in registers)
        if (tid < 64) {
            int ln = s_ln;
            ull cur = __shfl(rm, c);
            ull avail = ~cur;
            while (avail != 0ull && ln < MAX_OUT) {
                int b = __ffsll(avail) - 1;
                int r = base + b;                      // pick
                if (tid == 0) s_kept[ln] = ssidx[r];
                ull row = (tid < 32) ? ubuf[b * 32 + tid] : 0ull;
                rm |= row;
                if (tid == c) rm |= (1ull << b);       // remove the pick itself
                ln++;
                cur = __shfl(rm, c);
                avail = ~cur;
            }
            if (tid == 0) s_ln = ln;
        }
        __syncthreads();
    }

    bool need = (s_ln < MAX_OUT);        // exhaustion guard (candidates < VT exist)
    if (tid == 0) *flag = need ? 1 : 0;
    if (need) return;                    // k_slow takes over (exact)
    if (tid < MAX_OUT) write_row(reg, anc, lnd, tid, s_kept[tid], out);
}

// ---------- kernel 3: exact self-contained fallback (flag-gated; never runs) ----------
__global__ void __launch_bounds__(BLK) k_slow(const float2* __restrict__ cls,
                                              const float4* __restrict__ reg,
                                              const float4* __restrict__ anc,
                                              const float* __restrict__ lnd, int n,
                                              const int* __restrict__ flag,
                                              float* __restrict__ sbuf,
                                              float* __restrict__ out) {
    if (*flag == 0) return;              // expected path: exit immediately
    __shared__ ull warr[NW];
    __shared__ ull s_win;
    __shared__ double s_pb[5];
    __shared__ int kidx[MAX_OUT];
    int tid = threadIdx.x;
    for (int i = tid; i < n; i += BLK) {
        float sc = cls[i].y;
        sbuf[i] = ((double)sc > 0.4) ? sc : 0.0f;
    }
    __syncthreads();
    int ln = 0;
    for (int oi = 0; oi < MAX_OUT; ++oi) {
        ull k = 0;
        for (int i = tid; i < n; i += BLK) {
            ull kk = ((ull)__float_as_uint(sbuf[i]) << 32)
                   | (ull)(0xFFFFFFFFu - (unsigned int)i);
            if (kk > k) k = kk;
        }
        k = wmax(k);
        if ((tid & 63) == 0) warr[tid >> 6] = k;
        __syncthreads();
        if (tid < 64) {
            ull v = (tid < NW) ? warr[tid] : 0ull;
            v = wmax(v);
            if (tid == 0) s_win = v;
        }
        __syncthreads();
        ull win = s_win;
        if ((win >> 32) == 0u) break;
        int pidx = (int)(0xFFFFFFFFu - (unsigned int)win);
        if (tid == 0) {
            double b[4];
            decode_box_d(reg, anc, pidx, b);
            s_pb[0] = b[0]; s_pb[1] = b[1]; s_pb[2] = b[2]; s_pb[3] = b[3];
            s_pb[4] = (b[2] - b[0]) * (b[3] - b[1]);
            kidx[oi] = pidx;
        }
        __syncthreads();
        double p0 = s_pb[0], p1 = s_pb[1], p2 = s_pb[2], p3 = s_pb[3], pa = s_pb[4];
        for (int i = tid; i < n; i += BLK) {
            float v = sbuf[i];
            if (v != 0.0f) {
                double b[4];
                decode_box_d(reg, anc, i, b);
                double ih = fmin(b[2], p2) - fmax(b[0], p0); ih = fmax(ih, 0.0);
                double iw = fmin(b[3], p3) - fmax(b[1], p1); iw = fmax(iw, 0.0);
                double inter = ih * iw;
                double aa = (b[2] - b[0]) * (b[3] - b[1]);
                double den = aa + pa; den = den - inter; den = den + 1e-12;
                if (inter / den > 0.4) sbuf[i] = 0.0f;   // kills the pick too
            }
        }
        __syncthreads();
        ln = oi + 1;
    }
    __syncthreads();
    if (tid < MAX_OUT)
        write_row(reg, anc, lnd, tid, (tid < ln) ? kidx[tid] : -1, out);
}

extern "C" void kernel_launch(void* const* d_in, const int* in_sizes, int n_in,
                              void* d_out, int out_size, void* d_ws, size_t ws_size,
                              hipStream_t stream) {
    const float2* cls = (const float2*)d_in[0];    // (N,2) f32
    const float4* reg = (const float4*)d_in[1];    // (N,4) f32
    const float*  lnd = (const float*)d_in[2];     // (N,10) f32
    const float4* anc = (const float4*)d_in[3];    // (N,4) f32
    const int n = N_ANCHORS;

    uint8_t* w = (uint8_t*)d_ws;
    int*   ctr  = (int*)w;                 //     0: 64 B
    int*   flag = (int*)(w + 64);          //    64: 64 B (always written by k_fused)
    ull*   keys = (ull*)(w + 128);         //   128: 16384 B
    float* sbuf = (float*)(w + 16512);     // 16512: N*4 B (fallback only)

    hipMemsetAsync(ctr, 0, 64, stream);
    int grid = (n + 255) / 256;
    k_compact_top<<<grid, 256, 0, stream>>>(cls, n, ctr, keys);
    k_fused<<<1, BLK, 0, stream>>>(reg, anc, lnd, ctr, keys, flag, (float*)d_out);
    k_slow<<<1, BLK, 0, stream>>>(cls, reg, anc, lnd, n, flag, sbuf, (float*)d_out);
}

// Round 14
// 241.938 us; speedup vs baseline: 1.4385x; 1.4385x over previous
//
#include <hip/hip_runtime.h>
#include <stdint.h>

// Match numpy semantics: no FMA contraction anywhere in decision-critical math.
#pragma clang fp contract(off)

#define N_ANCHORS 172032  // compile-time problem constant
#define MAX_OUT 200
#define KTOP 2048         // top-K prefix capacity
#define NCHUNK (KTOP / 64)
#define BLK 1024
#define NW (BLK / 64)
#define VT 2.35f          // fixed prefix threshold: scores ~ N(0,1) =>
                          // csel = 172032*P(N>2.35) ~ 1615 +/- 40 (5sig < 2048).
                          // rank_200 < 900 (round-5 evidence). Exact fallback
                          // guards both overflow and exhaustion.

typedef unsigned long long ull;

// f64 decode: f32 inputs upcast to f64, reference op order. Returns (y1,x1,y2,x2).
__device__ __forceinline__ void decode_box_d(const float4* __restrict__ reg,
                                             const float4* __restrict__ anc, int i,
                                             double b[4]) {
#pragma clang fp contract(off)
    float4 r = reg[i];
    float4 a = anc[i];
    double dx = (double)r.x * 0.1;
    double dy = (double)r.y * 0.1;
    double dw = (double)r.z * 0.2;
    double dh = (double)r.w * 0.2;
    double xa = (double)a.x, ya = (double)a.y, wa = (double)a.z, ha = (double)a.w;
    double xc = dx * wa; xc = xc + xa;     // dx*w_a + x_a
    double yc = dy * ha; yc = yc + ya;     // dy*h_a + y_a
    double w = exp(dw) * wa;
    double h = exp(dh) * ha;
    double h2 = h * 0.5, w2 = w * 0.5;
    b[0] = yc - h2; b[1] = xc - w2; b[2] = yc + h2; b[3] = xc + w2;
}

// Gather + f64 decode one output row (boxes + landmarks), write f32.
__device__ __forceinline__ void write_row(const float4* __restrict__ reg,
                                          const float4* __restrict__ anc,
                                          const float* __restrict__ lnd,
                                          int q, int idx, float* __restrict__ out) {
#pragma clang fp contract(off)
    float b[4] = {0.f, 0.f, 0.f, 0.f};
    float l10[10] = {0.f, 0.f, 0.f, 0.f, 0.f, 0.f, 0.f, 0.f, 0.f, 0.f};
    if (idx >= 0) {
        double bb[4];
        decode_box_d(reg, anc, idx, bb);
        b[0] = (float)bb[0]; b[1] = (float)bb[1]; b[2] = (float)bb[2]; b[3] = (float)bb[3];
        float4 a = anc[idx];
        double xa = (double)a.x, ya = (double)a.y, wa = (double)a.z, ha = (double)a.w;
        for (int j = 0; j < 5; ++j) {
            double lx = (double)lnd[idx * 10 + 2 * j]     * 0.1;
            double ly = (double)lnd[idx * 10 + 2 * j + 1] * 0.1;
            lx = lx * wa; lx = lx + xa;
            ly = ly * ha; ly = ly + ya;
            l10[2 * j] = (float)lx; l10[2 * j + 1] = (float)ly;
        }
    }
    for (int c = 0; c < 4; ++c)  out[q * 4 + c] = b[c];
    for (int c = 0; c < 10; ++c) out[MAX_OUT * 4 + q * 10 + c] = l10[c];
}

__device__ __forceinline__ ull wmax(ull k) {
    for (int d = 32; d > 0; d >>= 1) {
        ull o = __shfl_down(k, d, 64);
        if (o > k) k = o;
    }
    return k;
}

// ---------- kernel 1: compact top candidates — ONE global atomic per block ----------
__global__ void __launch_bounds__(BLK) k_compact_top(const float2* __restrict__ cls, int n,
                                                     int* __restrict__ ctr,
                                                     ull* __restrict__ keys) {
    __shared__ int wpre[16];
    __shared__ int bbase;
    int tid = threadIdx.x;
    int i = blockIdx.x * BLK + tid;
    bool c = false; ull key = 0ull;
    if (i < n) {
        float sc = cls[i].y;               // score = cls[:,1]
        if (sc > VT) {
            c = true;
            key = ((ull)__float_as_uint(sc) << 32)
                | (ull)(0xFFFFFFFFu - (unsigned int)i);
        }
    }
    ull m = __ballot(c);
    int wid = tid >> 6, lane = tid & 63;
    if (lane == 0) wpre[wid] = __popcll(m);
    __syncthreads();
    if (tid == 0) {
        int s = 0;
        for (int w2 = 0; w2 < 16; ++w2) { int t = wpre[w2]; wpre[w2] = s; s += t; }
        bbase = (s > 0) ? atomicAdd(&ctr[0], s) : 0;
    }
    __syncthreads();
    if (c) {
        int pos = bbase + wpre[wid] + __popcll(m & ((1ull << lane) - 1ull));
        if (pos < KTOP) keys[pos] = key;
    }
}

// ---------- kernel 2: fused bitonic sort + chunked diag-greedy NMS + output ----------
__global__ void __launch_bounds__(BLK) k_fused(const float4* __restrict__ reg,
                                               const float4* __restrict__ anc,
                                               const float* __restrict__ lnd,
                                               const int* __restrict__ ctr,
                                               const ull* __restrict__ gkeys,
                                               int* __restrict__ flag,
                                               float* __restrict__ out) {
    __shared__ ull sk[KTOP];             // 16 KB
    __shared__ float4 sbox[KTOP];        // 32 KB (rank order)
    __shared__ int ssidx[KTOP];          // 8 KB  (rank order)
    __shared__ unsigned int dmat[128];   // 64 rows x 2 words: in-chunk suppression
    __shared__ unsigned int s_rm[64];    // removed mask, 32 ranks/word
    __shared__ int s_kept[MAX_OUT];
    __shared__ int s_prk[64];            // this chunk's pick ranks
    __shared__ int s_ln, s_np;

    int tid = threadIdx.x;
    int csel = ctr[0];
    if (csel > KTOP) { if (tid == 0) *flag = 1; return; }   // overflow -> fallback

    for (int j = tid; j < KTOP; j += BLK) sk[j] = (j < csel) ? gkeys[j] : 0ull;
    if (tid == 0) s_ln = 0;
    __syncthreads();

    // bitonic sort desc (score desc, idx asc via ~idx) — validated rounds 2/11/12
    for (int k = 2; k <= KTOP; k <<= 1) {
        for (int j = k >> 1; j > 0; j >>= 1) {
            for (int i = tid; i < KTOP; i += BLK) {
                int l = i ^ j;
                if (l > i) {
                    bool desc = ((i & k) == 0);
                    ull a = sk[i], b = sk[l];
                    if (desc ? (a < b) : (a > b)) { sk[i] = b; sk[l] = a; }
                }
            }
            __syncthreads();
        }
    }

    // decode boxes into rank order; init removed mask (ranks >= csel pre-removed)
    for (int r = tid; r < KTOP; r += BLK) {
        if (r < csel) {
            int idx = (int)(0xFFFFFFFFu - (unsigned int)sk[r]);
            ssidx[r] = idx;
            double b[4];
            decode_box_d(reg, anc, idx, b);
            sbox[r] = make_float4((float)b[0], (float)b[1], (float)b[2], (float)b[3]);
        } else {
            ssidx[r] = -1;
            sbox[r] = make_float4(0.f, 0.f, 0.f, 0.f);
        }
    }
    for (int w = tid; w < 64; w += BLK) {
        int rb = w << 5;
        unsigned int m = 0u;
        if (rb >= csel) m = 0xFFFFFFFFu;
        else if (rb + 32 > csel) m = ~((1u << (csel - rb)) - 1u);
        s_rm[w] = m;
    }
    __syncthreads();

    for (int c = 0; c < NCHUNK; ++c) {
        int base = c << 6;
        if (base >= csel) break;                        // uniform
        if (tid < 128) dmat[tid] = 0u;
        __syncthreads();
        // diag 64x64 block: thread t -> row=t>>4, 4 cols (cg=t&15)
        {
            int row = tid >> 4, cg = tid & 15;
            float4 bi = sbox[base + row];
            double q0 = (double)bi.x, q1 = (double)bi.y, q2 = (double)bi.z, q3 = (double)bi.w;
            double ai = (q2 - q0) * (q3 - q1);
            unsigned int bits = 0;
            for (int e = 0; e < 4; ++e) {
                int col = (cg << 2) + e;
                if (col > row) {
                    float4 bj = sbox[base + col];
                    double y1 = (double)bj.x, x1 = (double)bj.y;
                    double y2 = (double)bj.z, x2 = (double)bj.w;
                    double ih = fmin(y2, q2) - fmax(y1, q0); ih = fmax(ih, 0.0);
                    double iw = fmin(x2, q3) - fmax(x1, q1); iw = fmax(iw, 0.0);
                    double inter = ih * iw;
                    double aj = (y2 - y1) * (x2 - x1);
                    double den = aj + ai; den = den - inter; den = den + 1e-12;
                    if (inter / den > 0.4) bits |= 1u << (col & 31);
                }
            }
            if (bits) atomicOr(&dmat[(row << 1) + (cg >> 3)], bits);
        }
        __syncthreads();
        // wave-0 scan: rows in registers, row fetch via shfl (no LDS in serial chain)
        if (tid < 64) {
            ull myrow = ((ull)dmat[tid << 1]) | (((ull)dmat[(tid << 1) + 1]) << 32);
            ull avail = ~(((ull)s_rm[c << 1]) | (((ull)s_rm[(c << 1) + 1]) << 32));
            int ln = s_ln;
            int np = 0;
            while (avail != 0ull && ln < MAX_OUT) {
                int b = __ffsll(avail) - 1;
                int r = base + b;
                if (tid == 0) { s_kept[ln] = ssidx[r]; s_prk[np] = r; }
                ln++; np++;
                ull rb = __shfl(myrow, b);
                avail &= ~rb;
                avail &= ~(1ull << b);
            }
            if (tid == 0) { s_ln = ln; s_np = np; }
        }
        __syncthreads();
        // deferred: suppress remaining ranks vs this chunk's actual picks
        int np = s_np;
        if (np > 0) {
            for (int j = base + 64 + tid; j < csel; j += BLK) {
                if (!((s_rm[j >> 5] >> (j & 31)) & 1u)) {
                    float4 bj = sbox[j];
                    double y1 = (double)bj.x, x1 = (double)bj.y;
                    double y2 = (double)bj.z, x2 = (double)bj.w;
                    double aj = (y2 - y1) * (x2 - x1);
                    for (int p = 0; p < np; ++p) {
                        float4 bp = sbox[s_prk[p]];
                        double p0 = (double)bp.x, p1 = (double)bp.y;
                        double p2 = (double)bp.z, p3 = (double)bp.w;
                        double ap = (p2 - p0) * (p3 - p1);
                        double ih = fmin(y2, p2) - fmax(y1, p0); ih = fmax(ih, 0.0);
                        double iw = fmin(x2, p3) - fmax(x1, p1); iw = fmax(iw, 0.0);
                        double inter = ih * iw;
                        double den = aj + ap; den = den - inter; den = den + 1e-12;
                        if (inter / den > 0.4) {
                            atomicOr(&s_rm[j >> 5], 1u << (j & 31));
                            break;
                        }
                    }
                }
            }
        }
        __syncthreads();
        if (s_ln >= MAX_OUT) break;                     // uniform after barrier
    }

    bool need = (s_ln < MAX_OUT);        // exhaustion guard (< VT candidates exist)
    if (tid == 0) *flag = need ? 1 : 0;
    if (need) return;                    // k_slow takes over (exact)
    if (tid < MAX_OUT) write_row(reg, anc, lnd, tid, s_kept[tid], out);
}

// ---------- kernel 3: exact self-contained fallback (flag-gated; never runs) ----------
__global__ void __launch_bounds__(BLK) k_slow(const float2* __restrict__ cls,
                                              const float4* __restrict__ reg,
                                              const float4* __restrict__ anc,
                                              const float* __restrict__ lnd, int n,
                                              const int* __restrict__ flag,
                                              float* __restrict__ sbuf,
                                              float* __restrict__ out) {
    if (*flag == 0) return;              // expected path: exit immediately
    __shared__ ull warr[NW];
    __shared__ ull s_win;
    __shared__ double s_pb[5];
    __shared__ int kidx[MAX_OUT];
    int tid = threadIdx.x;
    for (int i = tid; i < n; i += BLK) {
        float sc = cls[i].y;
        sbuf[i] = ((double)sc > 0.4) ? sc : 0.0f;
    }
    __syncthreads();
    int ln = 0;
    for (int oi = 0; oi < MAX_OUT; ++oi) {
        ull k = 0;
        for (int i = tid; i < n; i += BLK) {
            ull kk = ((ull)__float_as_uint(sbuf[i]) << 32)
                   | (ull)(0xFFFFFFFFu - (unsigned int)i);
            if (kk > k) k = kk;
        }
        k = wmax(k);
        if ((tid & 63) == 0) warr[tid >> 6] = k;
        __syncthreads();
        if (tid < 64) {
            ull v = (tid < NW) ? warr[tid] : 0ull;
            v = wmax(v);
            if (tid == 0) s_win = v;
        }
        __syncthreads();
        ull win = s_win;
        if ((win >> 32) == 0u) break;
        int pidx = (int)(0xFFFFFFFFu - (unsigned int)win);
        if (tid == 0) {
            double b[4];
            decode_box_d(reg, anc, pidx, b);
            s_pb[0] = b[0]; s_pb[1] = b[1]; s_pb[2] = b[2]; s_pb[3] = b[3];
            s_pb[4] = (b[2] - b[0]) * (b[3] - b[1]);
            kidx[oi] = pidx;
        }
        __syncthreads();
        double p0 = s_pb[0], p1 = s_pb[1], p2 = s_pb[2], p3 = s_pb[3], pa = s_pb[4];
        for (int i = tid; i < n; i += BLK) {
            float v = sbuf[i];
            if (v != 0.0f) {
                double b[4];
                decode_box_d(reg, anc, i, b);
                double ih = fmin(b[2], p2) - fmax(b[0], p0); ih = fmax(ih, 0.0);
                double iw = fmin(b[3], p3) - fmax(b[1], p1); iw = fmax(iw, 0.0);
                double inter = ih * iw;
                double aa = (b[2] - b[0]) * (b[3] - b[1]);
                double den = aa + pa; den = den - inter; den = den + 1e-12;
                if (inter / den > 0.4) sbuf[i] = 0.0f;   // kills the pick too
            }
        }
        __syncthreads();
        ln = oi + 1;
    }
    __syncthreads();
    if (tid < MAX_OUT)
        write_row(reg, anc, lnd, tid, (tid < ln) ? kidx[tid] : -1, out);
}

extern "C" void kernel_launch(void* const* d_in, const int* in_sizes, int n_in,
                              void* d_out, int out_size, void* d_ws, size_t ws_size,
                              hipStream_t stream) {
    const float2* cls = (const float2*)d_in[0];    // (N,2) f32
    const float4* reg = (const float4*)d_in[1];    // (N,4) f32
    const float*  lnd = (const float*)d_in[2];     // (N,10) f32
    const float4* anc = (const float4*)d_in[3];    // (N,4) f32
    const int n = N_ANCHORS;

    uint8_t* w = (uint8_t*)d_ws;
    int*   ctr  = (int*)w;                 //     0: 64 B
    int*   flag = (int*)(w + 64);          //    64: 64 B (always written by k_fused)
    ull*   keys = (ull*)(w + 128);         //   128: 16384 B
    float* sbuf = (float*)(w + 16512);     // 16512: N*4 B (fallback only)

    hipMemsetAsync(ctr, 0, 64, stream);
    int grid = (n + BLK - 1) / BLK;        // 168 blocks of 1024
    k_compact_top<<<grid, BLK, 0, stream>>>(cls, n, ctr, keys);
    k_fused<<<1, BLK, 0, stream>>>(reg, anc, lnd, ctr, keys, flag, (float*)d_out);
    k_slow<<<1, BLK, 0, stream>>>(cls, reg, anc, lnd, n, flag, sbuf, (float*)d_out);
}